// Round 9
// baseline (717.836 us; speedup 1.0000x reference)
//
#include <hip/hip_runtime.h>
#include <stdint.h>

#define N_NODES 50000
#define N_EDGES 800000
#define NODE_TILES 782              // ceil(50000/64)

#define SE   72    // e-tile stride (bf16)
#define SW2  72
#define SPQ  136   // pq kernel strides (K=128)
#define SN1  200   // Wn1T row stride (K=192)
#define SN2  264   // Wn2T row stride (K=256)
#define SH1  264   // h1 LDS tile stride (264*2B=528B; 132%32=4 -> uniform banks)

typedef short bf16x8 __attribute__((ext_vector_type(8)));
typedef unsigned short ushort8 __attribute__((ext_vector_type(8)));
typedef float f32x4  __attribute__((ext_vector_type(4)));

static __device__ __forceinline__ unsigned short f2bf(float f) {
  unsigned int x = __float_as_uint(f);
  unsigned int r = (x + 0x7fffu + ((x >> 16) & 1u)) >> 16;
  return (unsigned short)r;
}
static __device__ __forceinline__ float bf2f(unsigned short u) {
  return __uint_as_float(((unsigned int)u) << 16);
}
static __device__ __forceinline__ float silu_f(float x) {
  return x / (1.0f + __expf(-x));
}
static __device__ __forceinline__ bf16x8 pack8(float4 u, float4 v) {
  bf16x8 w;
  w[0] = (short)f2bf(u.x); w[1] = (short)f2bf(u.y);
  w[2] = (short)f2bf(u.z); w[3] = (short)f2bf(u.w);
  w[4] = (short)f2bf(v.x); w[5] = (short)f2bf(v.y);
  w[6] = (short)f2bf(v.z); w[7] = (short)f2bf(v.w);
  return w;
}

// ---------------------------------------------------------------------------
// prep: natural transposed bf16 weights + destination histogram.
// ---------------------------------------------------------------------------
__global__ void prep_hist(
    const int* __restrict__ eidx,
    const float* __restrict__ We1, const float* __restrict__ We2,
    const float* __restrict__ Wn1, const float* __restrict__ Wn2,
    unsigned short* __restrict__ WpqT, unsigned short* __restrict__ We2T,
    unsigned short* __restrict__ Wn1T, unsigned short* __restrict__ Wn2T,
    int* __restrict__ cnt)
{
  const int gid = blockIdx.x * 256 + threadIdx.x;
  const int gsz = gridDim.x * 256;
  for (int i = gid; i < 128 * SPQ; i += gsz) {
    int n = i / SPQ, k = i % SPQ;
    unsigned short v = 0;
    if (k < 128) v = (n < 64) ? f2bf(We1[k * 64 + n]) : f2bf(We1[(128 + k) * 64 + (n - 64)]);
    WpqT[i] = v;
  }
  for (int i = gid; i < 64 * SW2; i += gsz) {
    int n = i / SW2, k = i % SW2;
    We2T[i] = (k < 64) ? f2bf(We2[k * 64 + n]) : (unsigned short)0;
  }
  for (int i = gid; i < 256 * SN1; i += gsz) {
    int n = i / SN1, k = i % SN1;
    Wn1T[i] = (k < 192) ? f2bf(Wn1[k * 256 + n]) : (unsigned short)0;
  }
  for (int i = gid; i < 128 * SN2; i += gsz) {
    int n = i / SN2, k = i % SN2;
    Wn2T[i] = (k < 256) ? f2bf(Wn2[k * 128 + n]) : (unsigned short)0;
  }
  if (gid < N_EDGES) atomicAdd(&cnt[eidx[gid]], 1);
}

// ---------------------------------------------------------------------------
// scan: exclusive prefix of cnt -> rowptr[50001], cursor copy. 1 block.
// ---------------------------------------------------------------------------
__global__ __launch_bounds__(1024) void scan_kernel(
    const int* __restrict__ cnt, int* __restrict__ rowptr,
    int* __restrict__ cursor)
{
  __shared__ int wsum[16], woff[16];
  const int t = threadIdx.x;
  const int lane = t & 63, wid = t >> 6;
  const int base = t * 49;
  int loc[49];
  int s = 0;
  #pragma unroll
  for (int i = 0; i < 49; ++i) {
    int idx = base + i;
    int c = (idx < N_NODES) ? cnt[idx] : 0;
    loc[i] = s; s += c;
  }
  int v = s;
  #pragma unroll
  for (int o = 1; o < 64; o <<= 1) {
    int u = __shfl_up(v, o);
    if (lane >= o) v += u;
  }
  if (lane == 63) wsum[wid] = v;
  __syncthreads();
  if (t == 0) {
    int a = 0;
    for (int w = 0; w < 16; ++w) { woff[w] = a; a += wsum[w]; }
    rowptr[N_NODES] = a;
  }
  __syncthreads();
  const int texcl = woff[wid] + (v - s);
  #pragma unroll
  for (int i = 0; i < 49; ++i) {
    int idx = base + i;
    if (idx < N_NODES) {
      int r = texcl + loc[i];
      rowptr[idx] = r;
      cursor[idx] = r;
    }
  }
}

// ---------------------------------------------------------------------------
// fill: order[slot] = edge id (4-B scatter only).
// ---------------------------------------------------------------------------
__global__ void fill_kernel(const int* __restrict__ eidx,
                            int* __restrict__ cursor, int* __restrict__ order)
{
  int e = blockIdx.x * 256 + threadIdx.x;
  if (e < N_EDGES) {
    int d = eidx[e];
    int pos = atomicAdd(&cursor[d], 1);
    order[pos] = e;
  }
}

// ---------------------------------------------------------------------------
// pq: [P|Q] = H @ [We1[0:128] | We1[128:256]], bf16, natural layout.
// ---------------------------------------------------------------------------
__global__ __launch_bounds__(256, 2) void pq_kernel(
    const float* __restrict__ H, const unsigned short* __restrict__ WpqT,
    unsigned short* __restrict__ P, unsigned short* __restrict__ Q)
{
  __shared__ unsigned short As[64 * SPQ];
  __shared__ unsigned short Ws[128 * SPQ];

  const int tid  = threadIdx.x;
  const int lane = tid & 63;
  const int wv   = tid >> 6;
  const int lr   = lane & 15;
  const int lq   = lane >> 4;
  const int m0   = wv * 16;
  const int n0   = blockIdx.x * 64;

  for (int i = tid * 8; i < 128 * SPQ; i += 256 * 8)
    *(bf16x8*)&Ws[i] = *(const bf16x8*)&WpqT[i];
  {
    int le = tid >> 2, q = tid & 3;
    int node = n0 + le; if (node >= N_NODES) node = N_NODES - 1;
    const float* src = H + (long)node * 128 + q * 32;
    unsigned short* dst = &As[le * SPQ + q * 32];
    #pragma unroll
    for (int c = 0; c < 32; c += 8) {
      float4 u = *(const float4*)(src + c);
      float4 v = *(const float4*)(src + c + 4);
      *(bf16x8*)(dst + c) = pack8(u, v);
    }
  }
  __syncthreads();

  f32x4 zero4 = {0.f, 0.f, 0.f, 0.f};
  f32x4 acc[8];
  #pragma unroll
  for (int f = 0; f < 8; ++f) acc[f] = zero4;
  #pragma unroll
  for (int s = 0; s < 4; ++s) {
    int kb = s * 32 + lq * 8;
    bf16x8 a = *(const bf16x8*)&As[(m0 + lr) * SPQ + kb];
    #pragma unroll
    for (int f = 0; f < 8; ++f) {
      bf16x8 b = *(const bf16x8*)&Ws[(f * 16 + lr) * SPQ + kb];
      acc[f] = __builtin_amdgcn_mfma_f32_16x16x32_bf16(a, b, acc[f], 0, 0, 0);
    }
  }
  #pragma unroll
  for (int f = 0; f < 8; ++f) {
    #pragma unroll
    for (int r = 0; r < 4; ++r) {
      int node = n0 + m0 + lq * 4 + r;
      if (node < N_NODES) {
        if (f < 4) P[(long)node * 64 + f * 16 + lr] = f2bf(acc[f][r]);
        else       Q[(long)node * 64 + (f - 4) * 16 + lr] = f2bf(acc[f][r]);
      }
    }
  }
}

// ---------------------------------------------------------------------------
// edge_compute v4: ORIGINAL edge order, fully sequential in/out streams.
// Inline geometry + gate (cheap); P[i]/Q[j] random bf16 gathers (L2/L3);
// e = silu(P+Q+c); GEMM2 MFMA; em[e] sequential row store.
// ---------------------------------------------------------------------------
__global__ __launch_bounds__(256, 3) void edge_compute(
    const unsigned short* __restrict__ P, const unsigned short* __restrict__ Q,
    const int* __restrict__ eidx, const float* __restrict__ xyz,
    const float* __restrict__ estruct, const float* __restrict__ erest,
    const float* __restrict__ We1, const float* __restrict__ be1,
    const unsigned short* __restrict__ We2T, const float* __restrict__ be2,
    const float* __restrict__ Wg1, const float* __restrict__ bg1,
    const float* __restrict__ Wg2, const float* __restrict__ bg2,
    unsigned short* __restrict__ em)
{
  __shared__ unsigned short W2s[64 * SW2];     // 9.2 KB
  __shared__ unsigned short Es [4 * 16 * SE];  // 9.2 KB
  __shared__ float ss[4][16][8];               // struct f32 stage
  __shared__ float d2s[4][16];
  __shared__ float dls[4][16];
  __shared__ float gsm[4][16];

  const int tid  = threadIdx.x;
  const int lane = tid & 63;
  const int wv   = tid >> 6;
  const int lr   = lane & 15;
  const int lq   = lane >> 4;

  for (int i = tid * 8; i < 64 * SW2; i += 256 * 8)
    *(bf16x8*)&W2s[i] = *(const bf16x8*)&We2T[i];
  __syncthreads();

  float bias1[4], w256r[4], w257r[4], bias2[4], wst[4][8];
  #pragma unroll
  for (int f = 0; f < 4; ++f) {
    int n = f * 16 + lr;
    bias1[f] = be1[n];
    w256r[f] = We1[256 * 64 + n];
    w257r[f] = We1[257 * 64 + n];
    bias2[f] = be2[n];
    #pragma unroll
    for (int c = 0; c < 8; ++c) wst[f][c] = We1[(258 + c) * 64 + n];
  }
  unsigned short* Es_w = &Es[wv * 16 * SE];

  const int n_tiles = N_EDGES / 16;  // 50000
  for (int tile = blockIdx.x * 4 + wv; tile < n_tiles; tile += gridDim.x * 4) {
    const int e0 = tile * 16;

    // geometry + struct stage (lanes 0..15, one edge each; in-wave LDS)
    if (lane < 16) {
      int e = e0 + lane;
      int ni = eidx[e], nj = eidx[N_EDGES + e];
      float dx = xyz[ni * 3 + 0] - xyz[nj * 3 + 0];
      float dy = xyz[ni * 3 + 1] - xyz[nj * 3 + 1];
      float dz = xyz[ni * 3 + 2] - xyz[nj * 3 + 2];
      float d2 = dx * dx + dy * dy + dz * dz;
      float dist = sqrtf(d2 + 1e-9f);
      float rest = erest[e];
      d2s[wv][lane] = d2;
      dls[wv][lane] = (dist - rest) / (rest + 1e-9f);
      float4 s0 = *(const float4*)&estruct[e * 8];
      float4 s1 = *(const float4*)&estruct[e * 8 + 4];
      ss[wv][lane][0] = s0.x; ss[wv][lane][1] = s0.y;
      ss[wv][lane][2] = s0.z; ss[wv][lane][3] = s0.w;
      ss[wv][lane][4] = s1.x; ss[wv][lane][5] = s1.y;
      ss[wv][lane][6] = s1.z; ss[wv][lane][7] = s1.w;
    }

    // gate MLP fp32: 4 lanes per edge, 8 hidden each
    {
      int el = lane >> 2, part = lane & 3;
      float g0 = d2s[wv][el];
      float g1 = dls[wv][el];
      float partial = 0.f;
      #pragma unroll
      for (int hh = 0; hh < 8; ++hh) {
        int h = part * 8 + hh;
        float a = bg1[h] + g0 * Wg1[0 * 32 + h] + g1 * Wg1[1 * 32 + h];
        #pragma unroll
        for (int c = 0; c < 8; ++c) a += ss[wv][el][c] * Wg1[(2 + c) * 32 + h];
        partial += silu_f(a) * Wg2[h];
      }
      partial += __shfl_xor(partial, 1);
      partial += __shfl_xor(partial, 2);
      if (part == 0)
        gsm[wv][el] = 1.f / (1.f + __expf(-(partial + bg2[0])));
    }

    // per-lane rows m = lq*4+r: i/j sequential reads
    int iN[4], jN[4];
    #pragma unroll
    for (int r = 0; r < 4; ++r) {
      int e = e0 + lq * 4 + r;
      iN[r] = eidx[e];
      jN[r] = eidx[N_EDGES + e];
    }
    float d2v[4], dlv[4], gv[4], sreg[4][8];
    #pragma unroll
    for (int r = 0; r < 4; ++r) {
      int m = lq * 4 + r;
      d2v[r] = d2s[wv][m];
      dlv[r] = dls[wv][m];
      #pragma unroll
      for (int c = 0; c < 8; ++c) sreg[r][c] = ss[wv][m][c];
    }

    // P/Q gathers, natural layout (R5-measured pattern)
    float pv[4][4], qv[4][4];
    #pragma unroll
    for (int r = 0; r < 4; ++r) {
      #pragma unroll
      for (int f = 0; f < 4; ++f) {
        pv[r][f] = bf2f(P[(long)iN[r] * 64 + f * 16 + lr]);
        qv[r][f] = bf2f(Q[(long)jN[r] * 64 + f * 16 + lr]);
      }
    }

    // pre-activation + silu -> Es
    #pragma unroll
    for (int f = 0; f < 4; ++f) {
      #pragma unroll
      for (int r = 0; r < 4; ++r) {
        float v = pv[r][f] + qv[r][f] + bias1[f]
                + d2v[r] * w256r[f] + dlv[r] * w257r[f];
        #pragma unroll
        for (int c = 0; c < 8; ++c) v += sreg[r][c] * wst[f][c];
        Es_w[(lq * 4 + r) * SE + f * 16 + lr] = f2bf(silu_f(v));
      }
    }

    // GEMM2: e_msg = silu(e @ We2 + be2) * g
    f32x4 zero4 = {0.f, 0.f, 0.f, 0.f};
    f32x4 acc2[4];
    #pragma unroll
    for (int f = 0; f < 4; ++f) acc2[f] = zero4;
    #pragma unroll
    for (int s = 0; s < 2; ++s) {
      int kb = s * 32 + lq * 8;
      bf16x8 a = *(const bf16x8*)&Es_w[lr * SE + kb];
      #pragma unroll
      for (int f = 0; f < 4; ++f) {
        bf16x8 b = *(const bf16x8*)&W2s[(f * 16 + lr) * SW2 + kb];
        acc2[f] = __builtin_amdgcn_mfma_f32_16x16x32_bf16(a, b, acc2[f], 0, 0, 0);
      }
    }
    // sequential em store (edge order, natural row layout)
    for (int r = 0; r < 4; ++r) {
      float gg = gsm[wv][lq * 4 + r];
      #pragma unroll
      for (int f = 0; f < 4; ++f) {
        em[(long)(e0 + lq * 4 + r) * 64 + f * 16 + lr] =
            f2bf(silu_f(acc2[f][r] + bias2[f]) * gg);
      }
    }
  }
}

// ---------------------------------------------------------------------------
// aggregate: agg[n] = sum over CSR slots of em[order[p]] (random full-row
// reads, sequential slot range). bf16 out. 4 threads/node.
// ---------------------------------------------------------------------------
__global__ __launch_bounds__(256, 4) void aggregate_kernel(
    const unsigned short* __restrict__ em, const int* __restrict__ rowptr,
    const int* __restrict__ order, unsigned short* __restrict__ agg)
{
  const int t = threadIdx.x;
  const int n = blockIdx.x * 64 + (t >> 2);
  const int q = t & 3;
  if (n >= N_NODES) return;
  const int p0 = rowptr[n], p1 = rowptr[n + 1];
  float acc[16];
  #pragma unroll
  for (int c = 0; c < 16; ++c) acc[c] = 0.f;
  for (int p = p0; p < p1; ++p) {
    int e = order[p];
    const unsigned short* row = em + (long)e * 64 + q * 16;
    ushort8 a = *(const ushort8*)row;
    ushort8 b = *(const ushort8*)(row + 8);
    #pragma unroll
    for (int c = 0; c < 8; ++c) acc[c]     += bf2f(a[c]);
    #pragma unroll
    for (int c = 0; c < 8; ++c) acc[8 + c] += bf2f(b[c]);
  }
  ushort8 w0, w1;
  #pragma unroll
  for (int c = 0; c < 8; ++c) { w0[c] = f2bf(acc[c]); w1[c] = f2bf(acc[8 + c]); }
  *(ushort8*)&agg[(long)n * 64 + q * 16] = w0;
  *(ushort8*)&agg[(long)n * 64 + q * 16 + 8] = w1;
}

// ---------------------------------------------------------------------------
// node_fused: h1 = silu([H|agg]@Wn1+bn1) (C-frags) -> LDS transpose ->
// upd = h1@Wn2+bn2; x = H+upd; out = LN(x)*g+b. Weights from L2 (no LDS).
// ---------------------------------------------------------------------------
__global__ __launch_bounds__(256, 3) void node_fused_kernel(
    const float* __restrict__ H, const unsigned short* __restrict__ agg,
    const unsigned short* __restrict__ Wn1T, const float* __restrict__ bn1,
    const unsigned short* __restrict__ Wn2T, const float* __restrict__ bn2,
    const float* __restrict__ ln_g, const float* __restrict__ ln_b,
    float* __restrict__ out)
{
  __shared__ unsigned short h1t[64 * SH1];  // 33.8 KB

  const int tid  = threadIdx.x;
  const int lane = tid & 63;
  const int wv   = tid >> 6;
  const int lr   = lane & 15;
  const int lq   = lane >> 4;
  const int m0   = wv * 16;
  const int n0   = blockIdx.x * 64;

  int rowa = n0 + m0 + lr;
  if (rowa >= N_NODES) rowa = N_NODES - 1;

  // ---- phase 1: h1 tile ----
  f32x4 zero4 = {0.f, 0.f, 0.f, 0.f};
  f32x4 acc1[16];
  #pragma unroll
  for (int f = 0; f < 16; ++f) acc1[f] = zero4;
  #pragma unroll
  for (int s = 0; s < 6; ++s) {
    int kb = s * 32 + lq * 8;
    bf16x8 a;
    if (s < 4) {
      const float* p = H + (long)rowa * 128 + kb;
      float4 u = *(const float4*)p;
      float4 v = *(const float4*)(p + 4);
      a = pack8(u, v);
    } else {
      a = *(const bf16x8*)&agg[(long)rowa * 64 + (kb - 128)];
    }
    #pragma unroll
    for (int f = 0; f < 16; ++f) {
      bf16x8 b = *(const bf16x8*)&Wn1T[(long)(f * 16 + lr) * SN1 + kb];
      acc1[f] = __builtin_amdgcn_mfma_f32_16x16x32_bf16(a, b, acc1[f], 0, 0, 0);
    }
  }
  #pragma unroll
  for (int f = 0; f < 16; ++f) {
    float bias = bn1[f * 16 + lr];
    #pragma unroll
    for (int r = 0; r < 4; ++r)
      h1t[(m0 + lq * 4 + r) * SH1 + f * 16 + lr] = f2bf(silu_f(acc1[f][r] + bias));
  }
  __syncthreads();

  // ---- phase 2: upd + residual + LayerNorm ----
  f32x4 acc2[8];
  #pragma unroll
  for (int f = 0; f < 8; ++f) acc2[f] = zero4;
  #pragma unroll
  for (int s = 0; s < 8; ++s) {
    int kb = s * 32 + lq * 8;
    bf16x8 a = *(const bf16x8*)&h1t[(m0 + lr) * SH1 + kb];
    #pragma unroll
    for (int f = 0; f < 8; ++f) {
      bf16x8 b = *(const bf16x8*)&Wn2T[(long)(f * 16 + lr) * SN2 + kb];
      acc2[f] = __builtin_amdgcn_mfma_f32_16x16x32_bf16(a, b, acc2[f], 0, 0, 0);
    }
  }

  #pragma unroll
  for (int r = 0; r < 4; ++r) {
    int node = n0 + m0 + lq * 4 + r;
    int nc = node < N_NODES ? node : N_NODES - 1;
    float x[8];
    float sum = 0.f, sumsq = 0.f;
    #pragma unroll
    for (int f = 0; f < 8; ++f) {
      int n = f * 16 + lr;
      float u = acc2[f][r] + bn2[n];
      float xv = H[(long)nc * 128 + n] + u;
      x[f] = xv;
      sum += xv;
      sumsq += xv * xv;
    }
    #pragma unroll
    for (int o = 1; o < 16; o <<= 1) {
      sum   += __shfl_xor(sum, o);
      sumsq += __shfl_xor(sumsq, o);
    }
    float mu  = sum * (1.f / 128.f);
    float var = sumsq * (1.f / 128.f) - mu * mu;
    float rstd = rsqrtf(var + 1e-5f);
    if (node < N_NODES) {
      #pragma unroll
      for (int f = 0; f < 8; ++f) {
        int n = f * 16 + lr;
        out[(long)node * 128 + n] = (x[f] - mu) * rstd * ln_g[n] + ln_b[n];
      }
    }
  }
}

extern "C" void kernel_launch(void* const* d_in, const int* in_sizes, int n_in,
                              void* d_out, int out_size, void* d_ws, size_t ws_size,
                              hipStream_t stream) {
  const float* H       = (const float*)d_in[0];
  const float* xyz     = (const float*)d_in[1];
  const int*   eidx    = (const int*)d_in[2];
  const float* estruct = (const float*)d_in[3];
  const float* erest   = (const float*)d_in[4];
  const float* We1     = (const float*)d_in[5];
  const float* be1     = (const float*)d_in[6];
  const float* We2     = (const float*)d_in[7];
  const float* be2     = (const float*)d_in[8];
  const float* Wg1     = (const float*)d_in[9];
  const float* bg1     = (const float*)d_in[10];
  const float* Wg2     = (const float*)d_in[11];
  const float* bg2     = (const float*)d_in[12];
  const float* Wn1     = (const float*)d_in[13];
  const float* bn1     = (const float*)d_in[14];
  const float* Wn2     = (const float*)d_in[15];
  const float* bn2     = (const float*)d_in[16];
  const float* ln_g    = (const float*)d_in[17];
  const float* ln_b    = (const float*)d_in[18];

  char* ws = (char*)d_ws;
  unsigned short* em     = (unsigned short*)(ws + 0);           // 102,400,000
  int*            order  = (int*)(ws + 102400000);              //   3,200,000
  unsigned short* P      = (unsigned short*)(ws + 105600000);   //   6,400,000
  unsigned short* Qm     = (unsigned short*)(ws + 112000000);   //   6,400,000
  unsigned short* agg    = (unsigned short*)(ws + 118400000);   //   6,400,000
  int*            cnt    = (int*)(ws + 144000000);              //     200,192
  int*            rowptr = (int*)(ws + 144200192);              //     200,192
  int*            cursor = (int*)(ws + 144400384);              //     200,192
  unsigned short* WpqT   = (unsigned short*)(ws + 144600576);   //      34,816
  unsigned short* We2T   = (unsigned short*)(ws + 144635392);   //       9,216
  unsigned short* Wn1T   = (unsigned short*)(ws + 144644608);   //     102,400
  unsigned short* Wn2T   = (unsigned short*)(ws + 144747008);   //      67,584
  float* out = (float*)d_out;

  hipMemsetAsync(cnt, 0, (size_t)N_NODES * sizeof(int), stream);

  hipLaunchKernelGGL(prep_hist, dim3(3125), dim3(256), 0, stream,
                     eidx, We1, We2, Wn1, Wn2, WpqT, We2T, Wn1T, Wn2T, cnt);
  hipLaunchKernelGGL(scan_kernel, dim3(1), dim3(1024), 0, stream,
                     cnt, rowptr, cursor);
  hipLaunchKernelGGL(fill_kernel, dim3(3125), dim3(256), 0, stream,
                     eidx, cursor, order);
  hipLaunchKernelGGL(pq_kernel, dim3(NODE_TILES), dim3(256), 0, stream,
                     H, WpqT, P, Qm);
  hipLaunchKernelGGL(edge_compute, dim3(768), dim3(256), 0, stream,
                     P, Qm, eidx, xyz, estruct, erest,
                     We1, be1, We2T, be2, Wg1, bg1, Wg2, bg2, em);
  hipLaunchKernelGGL(aggregate_kernel, dim3(NODE_TILES), dim3(256), 0, stream,
                     em, rowptr, order, agg);
  hipLaunchKernelGGL(node_fused_kernel, dim3(NODE_TILES), dim3(256), 0, stream,
                     H, agg, Wn1T, bn1, Wn2T, bn2, ln_g, ln_b, out);
}

// Round 10
// 539.734 us; speedup vs baseline: 1.3300x; 1.3300x over previous
//
#include <hip/hip_runtime.h>
#include <stdint.h>

#define N_NODES 50000
#define N_EDGES 800000
#define NODE_TILES 782              // ceil(50000/64)

#define SE   72    // e-tile stride (bf16)
#define SW2  72
#define SPQ  136   // pq kernel strides (K=128)
#define SN1  200   // Wn1T row stride (K=192)
#define SN2  264   // Wn2T row stride (K=256)
#define SAG  72    // agg LDS tile stride
#define SH1  264   // h1 LDS tile stride

typedef short bf16x8 __attribute__((ext_vector_type(8)));
typedef unsigned short ushort8 __attribute__((ext_vector_type(8)));
typedef float f32x4  __attribute__((ext_vector_type(4)));

static __device__ __forceinline__ unsigned short f2bf(float f) {
  unsigned int x = __float_as_uint(f);
  unsigned int r = (x + 0x7fffu + ((x >> 16) & 1u)) >> 16;
  return (unsigned short)r;
}
static __device__ __forceinline__ float bf2f(unsigned short u) {
  return __uint_as_float(((unsigned int)u) << 16);
}
static __device__ __forceinline__ float silu_f(float x) {
  return x / (1.0f + __expf(-x));
}
static __device__ __forceinline__ bf16x8 pack8(float4 u, float4 v) {
  bf16x8 w;
  w[0] = (short)f2bf(u.x); w[1] = (short)f2bf(u.y);
  w[2] = (short)f2bf(u.z); w[3] = (short)f2bf(u.w);
  w[4] = (short)f2bf(v.x); w[5] = (short)f2bf(v.y);
  w[6] = (short)f2bf(v.z); w[7] = (short)f2bf(v.w);
  return w;
}

// ---------------------------------------------------------------------------
// prep: natural transposed bf16 weights + destination histogram.
// ---------------------------------------------------------------------------
__global__ void prep_hist(
    const int* __restrict__ eidx,
    const float* __restrict__ We1, const float* __restrict__ We2,
    const float* __restrict__ Wn1, const float* __restrict__ Wn2,
    unsigned short* __restrict__ WpqT, unsigned short* __restrict__ We2T,
    unsigned short* __restrict__ Wn1T, unsigned short* __restrict__ Wn2T,
    int* __restrict__ cnt)
{
  const int gid = blockIdx.x * 256 + threadIdx.x;
  const int gsz = gridDim.x * 256;
  for (int i = gid; i < 128 * SPQ; i += gsz) {
    int n = i / SPQ, k = i % SPQ;
    unsigned short v = 0;
    if (k < 128) v = (n < 64) ? f2bf(We1[k * 64 + n]) : f2bf(We1[(128 + k) * 64 + (n - 64)]);
    WpqT[i] = v;
  }
  for (int i = gid; i < 64 * SW2; i += gsz) {
    int n = i / SW2, k = i % SW2;
    We2T[i] = (k < 64) ? f2bf(We2[k * 64 + n]) : (unsigned short)0;
  }
  for (int i = gid; i < 256 * SN1; i += gsz) {
    int n = i / SN1, k = i % SN1;
    Wn1T[i] = (k < 192) ? f2bf(Wn1[k * 256 + n]) : (unsigned short)0;
  }
  for (int i = gid; i < 128 * SN2; i += gsz) {
    int n = i / SN2, k = i % SN2;
    Wn2T[i] = (k < 256) ? f2bf(Wn2[k * 128 + n]) : (unsigned short)0;
  }
  if (gid < N_EDGES) atomicAdd(&cnt[eidx[gid]], 1);
}

// ---------------------------------------------------------------------------
// scan: exclusive prefix of cnt -> rowptr[50001], cursor copy. 1 block.
// ---------------------------------------------------------------------------
__global__ __launch_bounds__(1024) void scan_kernel(
    const int* __restrict__ cnt, int* __restrict__ rowptr,
    int* __restrict__ cursor)
{
  __shared__ int wsum[16], woff[16];
  const int t = threadIdx.x;
  const int lane = t & 63, wid = t >> 6;
  const int base = t * 49;
  int loc[49];
  int s = 0;
  #pragma unroll
  for (int i = 0; i < 49; ++i) {
    int idx = base + i;
    int c = (idx < N_NODES) ? cnt[idx] : 0;
    loc[i] = s; s += c;
  }
  int v = s;
  #pragma unroll
  for (int o = 1; o < 64; o <<= 1) {
    int u = __shfl_up(v, o);
    if (lane >= o) v += u;
  }
  if (lane == 63) wsum[wid] = v;
  __syncthreads();
  if (t == 0) {
    int a = 0;
    for (int w = 0; w < 16; ++w) { woff[w] = a; a += wsum[w]; }
    rowptr[N_NODES] = a;
  }
  __syncthreads();
  const int texcl = woff[wid] + (v - s);
  #pragma unroll
  for (int i = 0; i < 49; ++i) {
    int idx = base + i;
    if (idx < N_NODES) {
      int r = texcl + loc[i];
      rowptr[idx] = r;
      cursor[idx] = r;
    }
  }
}

// ---------------------------------------------------------------------------
// fill: order[slot] = edge id (4-B scatter only).
// ---------------------------------------------------------------------------
__global__ void fill_kernel(const int* __restrict__ eidx,
                            int* __restrict__ cursor, int* __restrict__ order)
{
  int e = blockIdx.x * 256 + threadIdx.x;
  if (e < N_EDGES) {
    int d = eidx[e];
    int pos = atomicAdd(&cursor[d], 1);
    order[pos] = e;
  }
}

// ---------------------------------------------------------------------------
// reorder (R5-measured): one thread per CSR slot. Gathers per-edge metadata
// into slot order (sequential writes); computes d2/delta + gate MLP here.
// ---------------------------------------------------------------------------
__global__ void reorder_kernel(
    const int* __restrict__ eidx, const float* __restrict__ xyz,
    const float* __restrict__ estruct, const float* __restrict__ erest,
    const int* __restrict__ order,
    const float* __restrict__ Wg1, const float* __restrict__ bg1,
    const float* __restrict__ Wg2, const float* __restrict__ bg2,
    float4* __restrict__ metaA, unsigned short* __restrict__ sst,
    int* __restrict__ in_s)
{
  int s = blockIdx.x * 256 + threadIdx.x;
  if (s >= N_EDGES) return;
  int e = order[s];
  int i = eidx[e], j = eidx[N_EDGES + e];
  float dx = xyz[i * 3 + 0] - xyz[j * 3 + 0];
  float dy = xyz[i * 3 + 1] - xyz[j * 3 + 1];
  float dz = xyz[i * 3 + 2] - xyz[j * 3 + 2];
  float d2 = dx * dx + dy * dy + dz * dz;
  float dist = sqrtf(d2 + 1e-9f);
  float rest = erest[e];
  float dl = (dist - rest) / (rest + 1e-9f);
  float4 s0 = *(const float4*)&estruct[e * 8];
  float4 s1 = *(const float4*)&estruct[e * 8 + 4];
  float st[8] = {s0.x, s0.y, s0.z, s0.w, s1.x, s1.y, s1.z, s1.w};
  float gsum = 0.f;
  #pragma unroll
  for (int h = 0; h < 32; ++h) {
    float a = bg1[h] + d2 * Wg1[0 * 32 + h] + dl * Wg1[1 * 32 + h];
    #pragma unroll
    for (int c = 0; c < 8; ++c) a += st[c] * Wg1[(2 + c) * 32 + h];
    gsum += silu_f(a) * Wg2[h];
  }
  float g = 1.f / (1.f + __expf(-(gsum + bg2[0])));
  metaA[s] = make_float4(d2, dl, g, __int_as_float(j));
  ushort8 w;
  #pragma unroll
  for (int c = 0; c < 8; ++c) w[c] = f2bf(st[c]);
  *(ushort8*)&sst[(long)s * 8] = w;
  in_s[s] = i;
}

// ---------------------------------------------------------------------------
// pq: [P|Q] = H @ [We1[0:128] | We1[128:256]], bf16, natural layout.
// ---------------------------------------------------------------------------
__global__ __launch_bounds__(256, 2) void pq_kernel(
    const float* __restrict__ H, const unsigned short* __restrict__ WpqT,
    unsigned short* __restrict__ P, unsigned short* __restrict__ Q)
{
  __shared__ unsigned short As[64 * SPQ];
  __shared__ unsigned short Ws[128 * SPQ];

  const int tid  = threadIdx.x;
  const int lane = tid & 63;
  const int wv   = tid >> 6;
  const int lr   = lane & 15;
  const int lq   = lane >> 4;
  const int m0   = wv * 16;
  const int n0   = blockIdx.x * 64;

  for (int i = tid * 8; i < 128 * SPQ; i += 256 * 8)
    *(bf16x8*)&Ws[i] = *(const bf16x8*)&WpqT[i];
  {
    int le = tid >> 2, q = tid & 3;
    int node = n0 + le; if (node >= N_NODES) node = N_NODES - 1;
    const float* src = H + (long)node * 128 + q * 32;
    unsigned short* dst = &As[le * SPQ + q * 32];
    #pragma unroll
    for (int c = 0; c < 32; c += 8) {
      float4 u = *(const float4*)(src + c);
      float4 v = *(const float4*)(src + c + 4);
      *(bf16x8*)(dst + c) = pack8(u, v);
    }
  }
  __syncthreads();

  f32x4 zero4 = {0.f, 0.f, 0.f, 0.f};
  f32x4 acc[8];
  #pragma unroll
  for (int f = 0; f < 8; ++f) acc[f] = zero4;
  #pragma unroll
  for (int s = 0; s < 4; ++s) {
    int kb = s * 32 + lq * 8;
    bf16x8 a = *(const bf16x8*)&As[(m0 + lr) * SPQ + kb];
    #pragma unroll
    for (int f = 0; f < 8; ++f) {
      bf16x8 b = *(const bf16x8*)&Ws[(f * 16 + lr) * SPQ + kb];
      acc[f] = __builtin_amdgcn_mfma_f32_16x16x32_bf16(a, b, acc[f], 0, 0, 0);
    }
  }
  #pragma unroll
  for (int f = 0; f < 8; ++f) {
    #pragma unroll
    for (int r = 0; r < 4; ++r) {
      int node = n0 + m0 + lq * 4 + r;
      if (node < N_NODES) {
        if (f < 4) P[(long)node * 64 + f * 16 + lr] = f2bf(acc[f][r]);
        else       Q[(long)node * 64 + (f - 4) * 16 + lr] = f2bf(acc[f][r]);
      }
    }
  }
}

// ---------------------------------------------------------------------------
// edge_compute (R5-measured, 125 us / 63 MB FETCH): slot-ordered, sequential
// meta/sst/in_s streams, clustered P reads, random Q, natural layouts;
// em written sequentially in slot order.
// ---------------------------------------------------------------------------
__global__ __launch_bounds__(256, 3) void edge_compute(
    const unsigned short* __restrict__ P, const unsigned short* __restrict__ Q,
    const int* __restrict__ in_s,
    const float4* __restrict__ metaA, const unsigned short* __restrict__ sst,
    const float* __restrict__ We1, const float* __restrict__ be1,
    const unsigned short* __restrict__ We2T, const float* __restrict__ be2,
    unsigned short* __restrict__ em)
{
  __shared__ unsigned short W2s[64 * SW2];     // 9.2 KB
  __shared__ unsigned short Es [4 * 16 * SE];  // 9.2 KB
  __shared__ float4  mst[4][16];
  __shared__ ushort8 sstst[4][16];

  const int tid  = threadIdx.x;
  const int lane = tid & 63;
  const int wv   = tid >> 6;
  const int lr   = lane & 15;
  const int lq   = lane >> 4;

  for (int i = tid * 8; i < 64 * SW2; i += 256 * 8)
    *(bf16x8*)&W2s[i] = *(const bf16x8*)&We2T[i];
  __syncthreads();

  float bias1[4], w256r[4], w257r[4], bias2[4], wst[4][8];
  #pragma unroll
  for (int f = 0; f < 4; ++f) {
    int n = f * 16 + lr;
    bias1[f] = be1[n];
    w256r[f] = We1[256 * 64 + n];
    w257r[f] = We1[257 * 64 + n];
    bias2[f] = be2[n];
    #pragma unroll
    for (int c = 0; c < 8; ++c) wst[f][c] = We1[(258 + c) * 64 + n];
  }
  unsigned short* Es_w = &Es[wv * 16 * SE];

  const int n_tiles = N_EDGES / 16;  // 50000
  for (int tile = blockIdx.x * 4 + wv; tile < n_tiles; tile += gridDim.x * 4) {
    const int s0 = tile * 16;

    if (lane < 16) {
      mst[wv][lane]   = metaA[s0 + lane];
      sstst[wv][lane] = *(const ushort8*)&sst[(long)(s0 + lane) * 8];
    }

    int iN[4];
    #pragma unroll
    for (int r = 0; r < 4; ++r) iN[r] = in_s[s0 + lq * 4 + r];

    float d2v[4], dlv[4], gv[4], sreg[4][8];
    int jN[4];
    #pragma unroll
    for (int r = 0; r < 4; ++r) {
      int m = lq * 4 + r;
      float4 mm = mst[wv][m];
      d2v[r] = mm.x; dlv[r] = mm.y; gv[r] = mm.z;
      jN[r] = __float_as_int(mm.w);
      ushort8 sv = sstst[wv][m];
      #pragma unroll
      for (int c = 0; c < 8; ++c) sreg[r][c] = bf2f(sv[c]);
    }

    float pv[4][4], qv[4][4];
    #pragma unroll
    for (int r = 0; r < 4; ++r) {
      #pragma unroll
      for (int f = 0; f < 4; ++f) {
        pv[r][f] = bf2f(P[(long)iN[r] * 64 + f * 16 + lr]);
        qv[r][f] = bf2f(Q[(long)jN[r] * 64 + f * 16 + lr]);
      }
    }

    #pragma unroll
    for (int f = 0; f < 4; ++f) {
      #pragma unroll
      for (int r = 0; r < 4; ++r) {
        float v = pv[r][f] + qv[r][f] + bias1[f]
                + d2v[r] * w256r[f] + dlv[r] * w257r[f];
        #pragma unroll
        for (int c = 0; c < 8; ++c) v += sreg[r][c] * wst[f][c];
        Es_w[(lq * 4 + r) * SE + f * 16 + lr] = f2bf(silu_f(v));
      }
    }

    f32x4 zero4 = {0.f, 0.f, 0.f, 0.f};
    f32x4 acc2[4];
    #pragma unroll
    for (int f = 0; f < 4; ++f) acc2[f] = zero4;
    #pragma unroll
    for (int s = 0; s < 2; ++s) {
      int kb = s * 32 + lq * 8;
      bf16x8 a = *(const bf16x8*)&Es_w[lr * SE + kb];
      #pragma unroll
      for (int f = 0; f < 4; ++f) {
        bf16x8 b = *(const bf16x8*)&W2s[(f * 16 + lr) * SW2 + kb];
        acc2[f] = __builtin_amdgcn_mfma_f32_16x16x32_bf16(a, b, acc2[f], 0, 0, 0);
      }
    }
    #pragma unroll
    for (int f = 0; f < 4; ++f) {
      #pragma unroll
      for (int r = 0; r < 4; ++r) {
        float v = silu_f(acc2[f][r] + bias2[f]) * gv[r];
        em[(long)(s0 + lq * 4 + r) * 64 + f * 16 + lr] = f2bf(v);
      }
    }
  }
}

// ---------------------------------------------------------------------------
// node_fused: phase0 CSR-sum em (sequential, slot-ordered) -> LDS agg tile;
// phase1 h1 = silu([H|agg]@Wn1+bn1) -> LDS transpose; phase2 upd + residual
// + LayerNorm. Weights streamed from L2 (no weight LDS). 43 KB -> 3 blk/CU.
// ---------------------------------------------------------------------------
__global__ __launch_bounds__(256, 3) void node_fused_kernel(
    const float* __restrict__ H, const unsigned short* __restrict__ em,
    const int* __restrict__ rowptr,
    const unsigned short* __restrict__ Wn1T, const float* __restrict__ bn1,
    const unsigned short* __restrict__ Wn2T, const float* __restrict__ bn2,
    const float* __restrict__ ln_g, const float* __restrict__ ln_b,
    float* __restrict__ out)
{
  __shared__ unsigned short aggt[64 * SAG];  // 9.2 KB
  __shared__ unsigned short h1t [64 * SH1];  // 33.8 KB

  const int tid  = threadIdx.x;
  const int lane = tid & 63;
  const int wv   = tid >> 6;
  const int lr   = lane & 15;
  const int lq   = lane >> 4;
  const int m0   = wv * 16;
  const int n0   = blockIdx.x * 64;

  // ---- phase 0: aggregate em rows (sequential CSR range per node) ----
  {
    int le = tid >> 2, q = tid & 3;
    int node = n0 + le;
    float a16[16];
    #pragma unroll
    for (int c = 0; c < 16; ++c) a16[c] = 0.f;
    if (node < N_NODES) {
      int p0 = rowptr[node], p1 = rowptr[node + 1];
      for (int p = p0; p < p1; ++p) {
        const unsigned short* row = em + (long)p * 64 + q * 16;
        ushort8 a = *(const ushort8*)row;
        ushort8 b = *(const ushort8*)(row + 8);
        #pragma unroll
        for (int c = 0; c < 8; ++c) a16[c]     += bf2f(a[c]);
        #pragma unroll
        for (int c = 0; c < 8; ++c) a16[8 + c] += bf2f(b[c]);
      }
    }
    ushort8 w0, w1;
    #pragma unroll
    for (int c = 0; c < 8; ++c) { w0[c] = f2bf(a16[c]); w1[c] = f2bf(a16[8 + c]); }
    *(ushort8*)&aggt[le * SAG + q * 16]     = w0;
    *(ushort8*)&aggt[le * SAG + q * 16 + 8] = w1;
  }
  __syncthreads();

  // ---- phase 1: h1 tile ----
  int rowa = n0 + m0 + lr;
  int rowc = rowa < N_NODES ? rowa : N_NODES - 1;

  f32x4 zero4 = {0.f, 0.f, 0.f, 0.f};
  f32x4 acc1[16];
  #pragma unroll
  for (int f = 0; f < 16; ++f) acc1[f] = zero4;
  #pragma unroll
  for (int s = 0; s < 6; ++s) {
    int kb = s * 32 + lq * 8;
    bf16x8 a;
    if (s < 4) {
      const float* p = H + (long)rowc * 128 + kb;
      float4 u = *(const float4*)p;
      float4 v = *(const float4*)(p + 4);
      a = pack8(u, v);
    } else {
      a = *(const bf16x8*)&aggt[(m0 + lr) * SAG + (kb - 128)];
    }
    #pragma unroll
    for (int f = 0; f < 16; ++f) {
      bf16x8 b = *(const bf16x8*)&Wn1T[(long)(f * 16 + lr) * SN1 + kb];
      acc1[f] = __builtin_amdgcn_mfma_f32_16x16x32_bf16(a, b, acc1[f], 0, 0, 0);
    }
  }
  #pragma unroll
  for (int f = 0; f < 16; ++f) {
    float bias = bn1[f * 16 + lr];
    #pragma unroll
    for (int r = 0; r < 4; ++r)
      h1t[(m0 + lq * 4 + r) * SH1 + f * 16 + lr] = f2bf(silu_f(acc1[f][r] + bias));
  }
  __syncthreads();

  // ---- phase 2: upd + residual + LayerNorm ----
  f32x4 acc2[8];
  #pragma unroll
  for (int f = 0; f < 8; ++f) acc2[f] = zero4;
  #pragma unroll
  for (int s = 0; s < 8; ++s) {
    int kb = s * 32 + lq * 8;
    bf16x8 a = *(const bf16x8*)&h1t[(m0 + lr) * SH1 + kb];
    #pragma unroll
    for (int f = 0; f < 8; ++f) {
      bf16x8 b = *(const bf16x8*)&Wn2T[(long)(f * 16 + lr) * SN2 + kb];
      acc2[f] = __builtin_amdgcn_mfma_f32_16x16x32_bf16(a, b, acc2[f], 0, 0, 0);
    }
  }

  #pragma unroll
  for (int r = 0; r < 4; ++r) {
    int node = n0 + m0 + lq * 4 + r;
    int nc = node < N_NODES ? node : N_NODES - 1;
    float x[8];
    float sum = 0.f, sumsq = 0.f;
    #pragma unroll
    for (int f = 0; f < 8; ++f) {
      int n = f * 16 + lr;
      float u = acc2[f][r] + bn2[n];
      float xv = H[(long)nc * 128 + n] + u;
      x[f] = xv;
      sum += xv;
      sumsq += xv * xv;
    }
    #pragma unroll
    for (int o = 1; o < 16; o <<= 1) {
      sum   += __shfl_xor(sum, o);
      sumsq += __shfl_xor(sumsq, o);
    }
    float mu  = sum * (1.f / 128.f);
    float var = sumsq * (1.f / 128.f) - mu * mu;
    float rstd = rsqrtf(var + 1e-5f);
    if (node < N_NODES) {
      #pragma unroll
      for (int f = 0; f < 8; ++f) {
        int n = f * 16 + lr;
        out[(long)node * 128 + n] = (x[f] - mu) * rstd * ln_g[n] + ln_b[n];
      }
    }
  }
}

extern "C" void kernel_launch(void* const* d_in, const int* in_sizes, int n_in,
                              void* d_out, int out_size, void* d_ws, size_t ws_size,
                              hipStream_t stream) {
  const float* H       = (const float*)d_in[0];
  const float* xyz     = (const float*)d_in[1];
  const int*   eidx    = (const int*)d_in[2];
  const float* estruct = (const float*)d_in[3];
  const float* erest   = (const float*)d_in[4];
  const float* We1     = (const float*)d_in[5];
  const float* be1     = (const float*)d_in[6];
  const float* We2     = (const float*)d_in[7];
  const float* be2     = (const float*)d_in[8];
  const float* Wg1     = (const float*)d_in[9];
  const float* bg1     = (const float*)d_in[10];
  const float* Wg2     = (const float*)d_in[11];
  const float* bg2     = (const float*)d_in[12];
  const float* Wn1     = (const float*)d_in[13];
  const float* bn1     = (const float*)d_in[14];
  const float* Wn2     = (const float*)d_in[15];
  const float* bn2     = (const float*)d_in[16];
  const float* ln_g    = (const float*)d_in[17];
  const float* ln_b    = (const float*)d_in[18];

  char* ws = (char*)d_ws;
  unsigned short* em     = (unsigned short*)(ws + 0);           // 102,400,000
  float4*         metaA  = (float4*)(ws + 102400000);           //  12,800,000
  unsigned short* sst    = (unsigned short*)(ws + 115200000);   //  12,800,000
  int*            in_s   = (int*)(ws + 128000000);              //   3,200,000
  int*            order  = (int*)(ws + 131200000);              //   3,200,000 (dead after reorder)
  unsigned short* P      = (unsigned short*)(ws + 131200000);   //   6,400,000 (aliases order; pq runs after reorder)
  unsigned short* Qm     = (unsigned short*)(ws + 137600000);   //   6,400,000
  int*            cnt    = (int*)(ws + 144000000);              //     200,192
  int*            rowptr = (int*)(ws + 144200192);              //     200,192
  int*            cursor = (int*)(ws + 144400384);              //     200,192
  unsigned short* WpqT   = (unsigned short*)(ws + 144600576);   //      34,816
  unsigned short* We2T   = (unsigned short*)(ws + 144635392);   //       9,216
  unsigned short* Wn1T   = (unsigned short*)(ws + 144644608);   //     102,400
  unsigned short* Wn2T   = (unsigned short*)(ws + 144747008);   //      67,584
  float* out = (float*)d_out;

  hipMemsetAsync(cnt, 0, (size_t)N_NODES * sizeof(int), stream);

  hipLaunchKernelGGL(prep_hist, dim3(3125), dim3(256), 0, stream,
                     eidx, We1, We2, Wn1, Wn2, WpqT, We2T, Wn1T, Wn2T, cnt);
  hipLaunchKernelGGL(scan_kernel, dim3(1), dim3(1024), 0, stream,
                     cnt, rowptr, cursor);
  hipLaunchKernelGGL(fill_kernel, dim3(3125), dim3(256), 0, stream,
                     eidx, cursor, order);
  hipLaunchKernelGGL(reorder_kernel, dim3(3125), dim3(256), 0, stream,
                     eidx, xyz, estruct, erest, order,
                     Wg1, bg1, Wg2, bg2, metaA, sst, in_s);
  hipLaunchKernelGGL(pq_kernel, dim3(NODE_TILES), dim3(256), 0, stream,
                     H, WpqT, P, Qm);
  hipLaunchKernelGGL(edge_compute, dim3(768), dim3(256), 0, stream,
                     P, Qm, in_s, metaA, sst, We1, be1, We2T, be2, em);
  hipLaunchKernelGGL(node_fused_kernel, dim3(NODE_TILES), dim3(256), 0, stream,
                     H, em, rowptr, Wn1T, bn1, Wn2T, bn2, ln_g, ln_b, out);
}